// Round 5
// baseline (210.951 us; speedup 1.0000x reference)
//
#include <hip/hip_runtime.h>

typedef unsigned short u16;
typedef unsigned long long u64;
typedef __attribute__((ext_vector_type(4))) float f32x4;
typedef __attribute__((ext_vector_type(8))) short s16x8;
typedef __attribute__((ext_vector_type(4))) short s16x4;
typedef __attribute__((ext_vector_type(4))) unsigned int u32x4;

#define LDS_LOAD16(gp, lp) __builtin_amdgcn_global_load_lds( \
    (__attribute__((address_space(1))) void*)(gp), \
    (__attribute__((address_space(3))) void*)(lp), 16, 0, 0)

#define MFMA16 __builtin_amdgcn_mfma_f32_16x16x32_bf16

constexpr float L2E = 1.44269504088896340736f;

__device__ __forceinline__ u16 f2bf(float x) {
  unsigned u = __float_as_uint(x);
  u += 0x7FFF + ((u >> 16) & 1);   // RNE
  return (u16)(u >> 16);
}

__device__ __forceinline__ unsigned cvtpk_bf16(float lo, float hi) {
  unsigned r;
  asm("v_cvt_pk_bf16_f32 %0, %1, %2" : "=v"(r) : "v"(lo), "v"(hi));
  return r;
}

// ---------------------------------------------------------------- convert
struct ConvArgs {
  const float* src[7];
  u16* dst[7];
  int n4[7];
  float scale[7];
};

__global__ __launch_bounds__(256) void convert_many(ConvArgs a) {
  const int arr = blockIdx.y;
  const f32x4* src = (const f32x4*)a.src[arr];
  u16* dst = a.dst[arr];
  const int n4 = a.n4[arr];
  const float sc = a.scale[arr];
  const int stride = gridDim.x * blockDim.x;
  for (int i = blockIdx.x * blockDim.x + threadIdx.x; i < n4; i += stride) {
    f32x4 v = src[i];
    s16x4 o;
#pragma unroll
    for (int j = 0; j < 4; ++j) o[j] = (short)f2bf(v[j] * sc);
    *(s16x4*)(dst + (size_t)i * 4) = o;
  }
}

// ---------------------------------------------------------------- mask -> bits
__global__ __launch_bounds__(256) void mask_to_bits(const unsigned int* __restrict__ m32,
                                                    unsigned long long* __restrict__ bits,
                                                    int n) {
  const int i = blockIdx.x * blockDim.x + threadIdx.x;
  const int lane = threadIdx.x & 63;
  unsigned probe = m32[lane];
  bool bytemode = __any(probe > 1u);
  bool v;
  if (bytemode) v = ((const unsigned char*)m32)[i] != 0;
  else          v = m32[i] != 0;
  unsigned long long b = __ballot(v);
  if (lane == 0) bits[i >> 6] = b;
}

// ---------------------------------------------------------------- QKV GEMM (fused z)
// C[M,N] = A[M,K]*B[N,K]^T (+bias*bscale), bf16 out. 128x128 tile, swapped
// epilogue: lane holds C[row=..+c][col=..+g4+r] -> 8B packed stores.
struct QkvArgs {
  const u16* A[3];
  const u16* B[3];
  const float* bias[3];
  float bscale[3];
  u16* C[3];
};

__global__ __launch_bounds__(256) void gemm_qkv(QkvArgs a) {
  const int z = blockIdx.z;
  const u16* __restrict__ A = a.A[z];
  const u16* __restrict__ B = a.B[z];
  const float* __restrict__ bias = a.bias[z];
  const float bscale = a.bscale[z];
  u16* __restrict__ C = a.C[z];

  __shared__ u16 As[128 * 32];
  __shared__ u16 Bs[128 * 32];
  const int tid = threadIdx.x;
  const int lane = tid & 63;
  const int wave = tid >> 6;
  const int g = lane >> 4, c = lane & 15;
  const int g4 = g * 4;
  const int row0 = blockIdx.x * 128;
  const int col0 = blockIdx.y * 128;
  const int wr = (wave >> 1) * 64, wc = (wave & 1) * 64;

  f32x4 acc[4][4] = {};

  for (int k0 = 0; k0 < 1024; k0 += 32) {
    __syncthreads();
#pragma unroll
    for (int i = 0; i < 2; ++i) {
      int e = (i * 256 + tid) * 8;
      int r = e >> 5, cc = e & 31;
      LDS_LOAD16(A + (size_t)(row0 + r) * 1024 + k0 + cc, As + e);
      LDS_LOAD16(B + (size_t)(col0 + r) * 1024 + k0 + cc, Bs + e);
    }
    __syncthreads();
    s16x8 af[4], bf[4];
#pragma unroll
    for (int m = 0; m < 4; ++m) af[m] = *(const s16x8*)(As + (wr + m * 16 + c) * 32 + g * 8);
#pragma unroll
    for (int n = 0; n < 4; ++n) bf[n] = *(const s16x8*)(Bs + (wc + n * 16 + c) * 32 + g * 8);
#pragma unroll
    for (int m = 0; m < 4; ++m)
#pragma unroll
      for (int n = 0; n < 4; ++n)
        acc[m][n] = MFMA16(bf[n], af[m], acc[m][n], 0, 0, 0);   // swapped
  }

  f32x4 bv[4];
#pragma unroll
  for (int n = 0; n < 4; ++n) {
    bv[n] = *(const f32x4*)(bias + col0 + wc + n * 16 + g4);
#pragma unroll
    for (int r = 0; r < 4; ++r) bv[n][r] *= bscale;
  }
#pragma unroll
  for (int m = 0; m < 4; ++m)
#pragma unroll
    for (int n = 0; n < 4; ++n) {
      s16x4 o;
#pragma unroll
      for (int r = 0; r < 4; ++r) o[r] = (short)f2bf(acc[m][n][r] + bv[n][r]);
      *(s16x4*)(C + (size_t)(row0 + wr + m * 16 + c) * 1024 + col0 + wc + n * 16 + g4) = o;
    }
}

// ---------------------------------------------------------------- out GEMM
// 64x128 tile (512 blocks = 2/CU), fp32 out + residual, swapped epilogue.
__global__ __launch_bounds__(256) void gemm_out(const u16* __restrict__ A,
                                                const u16* __restrict__ B,
                                                const float* __restrict__ bias,
                                                const float* __restrict__ resid,
                                                float* __restrict__ C) {
  __shared__ u16 As[64 * 32];
  __shared__ u16 Bs[128 * 32];
  const int tid = threadIdx.x;
  const int lane = tid & 63;
  const int wave = tid >> 6;
  const int g = lane >> 4, c = lane & 15;
  const int g4 = g * 4;
  const int row0 = blockIdx.x * 64;
  const int col0 = blockIdx.y * 128;
  const int wr = (wave >> 1) * 32, wc = (wave & 1) * 64;

  f32x4 acc[2][4] = {};

  for (int k0 = 0; k0 < 1024; k0 += 32) {
    __syncthreads();
    LDS_LOAD16(A + (size_t)(row0 + (tid >> 2)) * 1024 + k0 + (tid & 3) * 8, As + tid * 8);
#pragma unroll
    for (int i = 0; i < 2; ++i) {
      int e = (i * 256 + tid) * 8;
      int r = e >> 5, cc = e & 31;
      LDS_LOAD16(B + (size_t)(col0 + r) * 1024 + k0 + cc, Bs + e);
    }
    __syncthreads();
    s16x8 af[2], bf[4];
#pragma unroll
    for (int m = 0; m < 2; ++m) af[m] = *(const s16x8*)(As + (wr + m * 16 + c) * 32 + g * 8);
#pragma unroll
    for (int n = 0; n < 4; ++n) bf[n] = *(const s16x8*)(Bs + (wc + n * 16 + c) * 32 + g * 8);
#pragma unroll
    for (int m = 0; m < 2; ++m)
#pragma unroll
      for (int n = 0; n < 4; ++n)
        acc[m][n] = MFMA16(bf[n], af[m], acc[m][n], 0, 0, 0);   // swapped
  }

  f32x4 bv[4];
#pragma unroll
  for (int n = 0; n < 4; ++n) bv[n] = *(const f32x4*)(bias + col0 + wc + n * 16 + g4);
#pragma unroll
  for (int m = 0; m < 2; ++m)
#pragma unroll
    for (int n = 0; n < 4; ++n) {
      size_t off = (size_t)(row0 + wr + m * 16 + c) * 1024 + col0 + wc + n * 16 + g4;
      f32x4 rv = *(const f32x4*)(resid + off);
      f32x4 o;
#pragma unroll
      for (int r = 0; r < 4; ++r) o[r] = acc[m][n][r] + bv[n][r] + rv[r];
      *(f32x4*)(C + off) = o;
    }
}

// ---------------------------------------------------------------- attention
// Swapped-operand flash attention. KVBLK=128, 16 iterations, ONE barrier/iter.
// K read directly from global (L1/L2); V double-buffered in LDS (XOR swizzle,
// 4-key-packed b64 writes). Fixed m=0 softmax in exp2 domain (Q pre-scaled by
// 0.125*log2e); per-lane partial denominators reduced in the epilogue.
constexpr float NEGV = -10000000.0f;

__global__ __launch_bounds__(256, 2) void attn_kernel(const u16* __restrict__ Qh,
                                                      const u16* __restrict__ Kh,
                                                      const u16* __restrict__ Vh,
                                                      const u64* __restrict__ mbits,
                                                      const float* __restrict__ head_mask,
                                                      u16* __restrict__ ctx) {
  __shared__ u16 Vt[2][64 * 136];   // [buf][d][key ^ 8*(d>>3)], stride 136

  const int tid = threadIdx.x;
  const int lane = tid & 63;
  const int wave = tid >> 6;
  const int g = lane >> 4, c = lane & 15;
  const int g4 = g * 4;
  // XCD-chunked swizzle: 512 = 8 XCDs x 64; same-(b,h) blocks colocate per XCD
  const int wid = (blockIdx.x & 7) * 64 + (blockIdx.x >> 3);
  const int qt = wid & 15;
  const int bh = wid >> 4;
  const int b = bh >> 4;
  const int h = bh & 15;
  const size_t rowbase = (size_t)b * 2048;
  const int D = 1024;

  // Q B-fragments, 2 q-subtiles: lane(c,g) holds Q[q=c][ks*32+g*8+j]
  s16x8 qf[2][2];
#pragma unroll
  for (int s = 0; s < 2; ++s) {
    const int qrow = qt * 128 + s * 64 + wave * 16 + c;
#pragma unroll
    for (int ks = 0; ks < 2; ++ks)
      qf[s][ks] = *(const s16x8*)(Qh + (rowbase + qrow) * D + h * 64 + ks * 32 + g * 8);
  }

  f32x4 accO[2][4] = {};        // [set][d0]; col q=c, reg r <-> d=d0*16+g4+r
  float srun[2] = {0.f, 0.f};

  const u64* mrow0 = mbits + (rowbase + qt * 128 + 0 * 64 + wave * 16 + c) * 32;
  const u64* mrow1 = mbits + (rowbase + qt * 128 + 1 * 64 + wave * 16 + c) * 32;

  const u16* Kbase = Kh + rowbase * D + h * 64;
  const u16* Vbase = Vh + rowbase * D + h * 64;

  // V staging slot: keys 4a..4a+3 (a = tid>>3), d-chunk (tid&7)*8
  const int aV = tid >> 3;
  const int sV = tid & 7;
  const int dcV = sV * 8;
  const int colV = (4 * aV) ^ (8 * sV);

  s16x8 vreg[4];
#define LOADV(kb_) { _Pragma("unroll") \
    for (int i = 0; i < 4; ++i) \
      vreg[i] = *(const s16x8*)(Vbase + (size_t)((kb_) + 4 * aV + i) * D + dcV); }
#define WRITEV(p_) { _Pragma("unroll") \
    for (int j = 0; j < 8; ++j) { \
      u64 w = (u64)(u16)vreg[0][j] | ((u64)(u16)vreg[1][j] << 16) | \
              ((u64)(u16)vreg[2][j] << 32) | ((u64)(u16)vreg[3][j] << 48); \
      *(u64*)(&Vt[p_][(dcV + j) * 136 + colV]) = w; } }

  LOADV(0);
  WRITEV(0);
  LOADV(128);
  __syncthreads();

  const int srcA = c + ((g & 1) << 5);
  const int srcB = srcA + 16;
  const bool hi = (g >> 1) != 0;

  for (int it = 0; it < 16; ++it) {
    const int p = it & 1;
    // stage V(it+1) -> Vt[p^1] (vmcnt already drained by barrier -> free)
    if (it < 15) WRITEV(p ^ 1);
    // prefetch V(it+2)
    if (it < 14) LOADV((it + 2) * 128);

    const int kb = it * 128;
    const u16* Kt = Kbase + (size_t)kb * D;

    // mask words for this 128-key tile
    u64 s0w0 = mrow0[it * 2], s0w1 = mrow0[it * 2 + 1];
    u64 s1w0 = mrow1[it * 2], s1w1 = mrow1[it * 2 + 1];
    u64 a0 = s0w0 >> g4, a1 = s0w1 >> g4, b0 = s1w0 >> g4, b1 = s1w1 >> g4;
    unsigned msk0[4] = {(unsigned)a0, (unsigned)(a0 >> 32), (unsigned)a1, (unsigned)(a1 >> 32)};
    unsigned msk1[4] = {(unsigned)b0, (unsigned)(b0 >> 32), (unsigned)b1, (unsigned)(b1 >> 32)};

    unsigned pkA[2][8], pkB[2][8];
    float sp0 = 0.f, sp1 = 0.f;

    // ---- QK^T + fused softmax per 16-key subtile (K straight from global)
#pragma unroll
    for (int t = 0; t < 8; ++t) {
      s16x8 kf0 = *(const s16x8*)(Kt + (size_t)(t * 16 + c) * D + g * 8);
      s16x8 kf1 = *(const s16x8*)(Kt + (size_t)(t * 16 + c) * D + 32 + g * 8);
      f32x4 z0 = {0.f, 0.f, 0.f, 0.f};
      z0 = MFMA16(kf0, qf[0][0], z0, 0, 0, 0);
      f32x4 aS0 = MFMA16(kf1, qf[0][1], z0, 0, 0, 0);
      f32x4 z1 = {0.f, 0.f, 0.f, 0.f};
      z1 = MFMA16(kf0, qf[1][0], z1, 0, 0, 0);
      f32x4 aS1 = MFMA16(kf1, qf[1][1], z1, 0, 0, 0);

      const unsigned m0 = msk0[t >> 1], m1 = msk1[t >> 1];
      const int bb = (t & 1) * 16;
#pragma unroll
      for (int r = 0; r < 4; ++r) {
        if ((m0 >> (bb + r)) & 1) aS0[r] = NEGV;
        if ((m1 >> (bb + r)) & 1) aS1[r] = NEGV;
        float p0 = exp2f(aS0[r]);  // Q pre-scaled by log2e -> this is exp(S)
        float p1 = exp2f(aS1[r]);
        aS0[r] = p0; aS1[r] = p1;
        sp0 += p0; sp1 += p1;
      }
      pkA[0][t] = cvtpk_bf16(aS0[0], aS0[1]);
      pkB[0][t] = cvtpk_bf16(aS0[2], aS0[3]);
      pkA[1][t] = cvtpk_bf16(aS1[0], aS1[1]);
      pkB[1][t] = cvtpk_bf16(aS1[2], aS1[3]);
    }
    srun[0] += sp0;
    srun[1] += sp1;

    // ---- P redistribution: C-layout -> A-fragments via shfl (proven)
    s16x8 pa[2][4];
#pragma unroll
    for (int s = 0; s < 2; ++s)
#pragma unroll
      for (int ks = 0; ks < 4; ++ks) {
        unsigned x0 = __shfl(pkA[s][2 * ks], srcA, 64), y0 = __shfl(pkA[s][2 * ks + 1], srcA, 64);
        unsigned x1 = __shfl(pkB[s][2 * ks], srcA, 64), y1 = __shfl(pkB[s][2 * ks + 1], srcA, 64);
        unsigned x2 = __shfl(pkA[s][2 * ks], srcB, 64), y2 = __shfl(pkA[s][2 * ks + 1], srcB, 64);
        unsigned x3 = __shfl(pkB[s][2 * ks], srcB, 64), y3 = __shfl(pkB[s][2 * ks + 1], srcB, 64);
        union { u32x4 u; s16x8 v; } w;
        w.u = (u32x4){hi ? y0 : x0, hi ? y1 : x1, hi ? y2 : x2, hi ? y3 : x3};
        pa[s][ks] = w.v;
      }

    // ---- PV from Vt[p]
    const u16* VtP = &Vt[p][0];
#pragma unroll
    for (int d0 = 0; d0 < 4; ++d0) {
      const int sw = d0 * 2 + (c >> 3);
#pragma unroll
      for (int ks = 0; ks < 4; ++ks) {
        s16x8 vb = *(const s16x8*)(VtP + (d0 * 16 + c) * 136 + (((ks * 32 + g * 8) ^ (sw * 8))));
        accO[0][d0] = MFMA16(vb, pa[0][ks], accO[0][d0], 0, 0, 0);
        accO[1][d0] = MFMA16(vb, pa[1][ks], accO[1][d0], 0, 0, 0);
      }
    }
    __syncthreads();
  }

  // ---- epilogue
  const float hm = head_mask[0];
#pragma unroll
  for (int s = 0; s < 2; ++s) {
    float tot = srun[s];
    tot += __shfl_xor(tot, 16, 64);
    tot += __shfl_xor(tot, 32, 64);
    float inv = hm / tot;
    const int qrow = qt * 128 + s * 64 + wave * 16 + c;
#pragma unroll
    for (int d0 = 0; d0 < 4; ++d0) {
      s16x4 o;
#pragma unroll
      for (int r = 0; r < 4; ++r) o[r] = (short)f2bf(accO[s][d0][r] * inv);
      *(s16x4*)(ctx + (rowbase + qrow) * D + h * 64 + d0 * 16 + g4) = o;
    }
  }
}

// ---------------------------------------------------------------- launch
extern "C" void kernel_launch(void* const* d_in, const int* in_sizes, int n_in,
                              void* d_out, int out_size, void* d_ws, size_t ws_size,
                              hipStream_t stream) {
  const float* q  = (const float*)d_in[0];
  const float* k  = (const float*)d_in[1];
  const float* v  = (const float*)d_in[2];
  const void*  am = d_in[3];
  const float* hm = (const float*)d_in[4];
  const float* Wq = (const float*)d_in[5];
  const float* bq = (const float*)d_in[6];
  const float* Wk = (const float*)d_in[7];
  const float* bk = (const float*)d_in[8];
  const float* Wv = (const float*)d_in[9];
  const float* bv = (const float*)d_in[10];
  const float* Wo = (const float*)d_in[11];
  const float* bo = (const float*)d_in[12];

  char* ws = (char*)d_ws;
  const size_t MB = 1024 * 1024;
  const bool big = ws_size >= 57 * MB;

  u16 *qb, *kb, *vb, *wqb, *wkb, *wvb, *wob, *Qh, *Kh, *Vh, *ctx;
  unsigned long long* mbits;
  if (big) {
    qb  = (u16*)(ws + 0 * MB);   kb  = (u16*)(ws + 8 * MB);   vb  = (u16*)(ws + 16 * MB);
    wqb = (u16*)(ws + 24 * MB);  wkb = (u16*)(ws + 26 * MB);
    wvb = (u16*)(ws + 28 * MB);  wob = (u16*)(ws + 30 * MB);
    Qh  = (u16*)(ws + 32 * MB);  Kh  = (u16*)(ws + 40 * MB);  Vh = (u16*)(ws + 48 * MB);
    mbits = (unsigned long long*)(ws + 56 * MB);
    ctx = qb;                    // free after QKV GEMMs
  } else {
    qb  = (u16*)(ws + 0 * MB);   kb  = (u16*)(ws + 8 * MB);   vb  = (u16*)(ws + 16 * MB);
    wqb = (u16*)(ws + 24 * MB);  wkb = (u16*)(ws + 26 * MB);
    wvb = (u16*)(ws + 28 * MB);  wob = (u16*)(ws + 30 * MB);
    Qh  = (u16*)(ws + 32 * MB);
    mbits = (unsigned long long*)(ws + 40 * MB);
    Kh = qb; Vh = kb; ctx = vb;  // round-4 sequential aliasing
  }

  ConvArgs ca;
  ca.src[0] = q;  ca.dst[0] = qb;  ca.n4[0] = 1048576; ca.scale[0] = 1.f;
  ca.src[1] = k;  ca.dst[1] = kb;  ca.n4[1] = 1048576; ca.scale[1] = 1.f;
  ca.src[2] = v;  ca.dst[2] = vb;  ca.n4[2] = 1048576; ca.scale[2] = 1.f;
  ca.src[3] = Wq; ca.dst[3] = wqb; ca.n4[3] = 262144;  ca.scale[3] = 0.125f * L2E;
  ca.src[4] = Wk; ca.dst[4] = wkb; ca.n4[4] = 262144;  ca.scale[4] = 1.f;
  ca.src[5] = Wv; ca.dst[5] = wvb; ca.n4[5] = 262144;  ca.scale[5] = 1.f;
  ca.src[6] = Wo; ca.dst[6] = wob; ca.n4[6] = 262144;  ca.scale[6] = 1.f;
  convert_many<<<dim3(256, 7), 256, 0, stream>>>(ca);

  mask_to_bits<<<32768, 256, 0, stream>>>((const unsigned int*)am, mbits, 8388608);

  QkvArgs ga;
  ga.A[0] = qb; ga.B[0] = wqb; ga.bias[0] = bq; ga.bscale[0] = 0.125f * L2E; ga.C[0] = Qh;
  ga.A[1] = kb; ga.B[1] = wkb; ga.bias[1] = bk; ga.bscale[1] = 1.f;          ga.C[1] = Kh;
  ga.A[2] = vb; ga.B[2] = wvb; ga.bias[2] = bv; ga.bscale[2] = 1.f;          ga.C[2] = Vh;
  if (big) {
    gemm_qkv<<<dim3(32, 8, 3), 256, 0, stream>>>(ga);
  } else {
    // sequential to respect aliasing (Kh=qb read by z=0, etc.)
    QkvArgs g1 = ga, g2 = ga, g3 = ga;
    g2.A[0] = ga.A[1]; g2.B[0] = ga.B[1]; g2.bias[0] = ga.bias[1]; g2.bscale[0] = ga.bscale[1]; g2.C[0] = ga.C[1];
    g3.A[0] = ga.A[2]; g3.B[0] = ga.B[2]; g3.bias[0] = ga.bias[2]; g3.bscale[0] = ga.bscale[2]; g3.C[0] = ga.C[2];
    gemm_qkv<<<dim3(32, 8, 1), 256, 0, stream>>>(g1);
    gemm_qkv<<<dim3(32, 8, 1), 256, 0, stream>>>(g2);
    gemm_qkv<<<dim3(32, 8, 1), 256, 0, stream>>>(g3);
  }

  attn_kernel<<<512, 256, 0, stream>>>(Qh, Kh, Vh, mbits, hm, ctx);

  gemm_out<<<dim3(64, 8), 256, 0, stream>>>(ctx, wob, bo, q, (float*)d_out);
}

// Round 6
// 155.081 us; speedup vs baseline: 1.3603x; 1.3603x over previous
//
#include <hip/hip_runtime.h>

typedef unsigned short u16;
typedef unsigned long long u64;
typedef __attribute__((ext_vector_type(4))) float f32x4;
typedef __attribute__((ext_vector_type(8))) short s16x8;
typedef __attribute__((ext_vector_type(4))) short s16x4;
typedef __attribute__((ext_vector_type(4))) unsigned int u32x4;
typedef __attribute__((ext_vector_type(2))) unsigned int u32x2;

#define LDS_LOAD16(gp, lp) __builtin_amdgcn_global_load_lds( \
    (__attribute__((address_space(1))) void*)(gp), \
    (__attribute__((address_space(3))) void*)(lp), 16, 0, 0)

#define MFMA16 __builtin_amdgcn_mfma_f32_16x16x32_bf16

constexpr float L2E = 1.44269504088896340736f;

__device__ __forceinline__ u16 f2bf(float x) {
  unsigned u = __float_as_uint(x);
  u += 0x7FFF + ((u >> 16) & 1);   // RNE
  return (u16)(u >> 16);
}

__device__ __forceinline__ unsigned cvtpk_bf16(float lo, float hi) {
  unsigned r;
  asm("v_cvt_pk_bf16_f32 %0, %1, %2" : "=v"(r) : "v"(lo), "v"(hi));
  return r;
}

// ---------------------------------------------------------------- convert (weights only)
struct ConvArgs {
  const float* src[4];
  u16* dst[4];
  float scale[4];
};

__global__ __launch_bounds__(256) void convert_many(ConvArgs a) {
  const int arr = blockIdx.y;
  const f32x4* src = (const f32x4*)a.src[arr];
  u16* dst = a.dst[arr];
  const float sc = a.scale[arr];
  const int stride = gridDim.x * blockDim.x;
  for (int i = blockIdx.x * blockDim.x + threadIdx.x; i < 262144; i += stride) {
    f32x4 v = src[i];
    s16x4 o;
#pragma unroll
    for (int j = 0; j < 4; ++j) o[j] = (short)f2bf(v[j] * sc);
    *(s16x4*)(dst + (size_t)i * 4) = o;
  }
}

// ---------------------------------------------------------------- mask -> bits
__global__ __launch_bounds__(256) void mask_to_bits(const unsigned int* __restrict__ m32,
                                                    unsigned long long* __restrict__ bits,
                                                    int n) {
  const int i = blockIdx.x * blockDim.x + threadIdx.x;
  const int lane = threadIdx.x & 63;
  unsigned probe = m32[lane];
  bool bytemode = __any(probe > 1u);
  bool v;
  if (bytemode) v = ((const unsigned char*)m32)[i] != 0;
  else          v = m32[i] != 0;
  unsigned long long b = __ballot(v);
  if (lane == 0) bits[i >> 6] = b;
}

// ---------------------------------------------------------------- QKV GEMM
// C[M,N] = A[M,K]*B[N,K]^T (+bias*bscale), A read as fp32 + in-reg cvt,
// double-buffered LDS, ONE barrier per k-step. Swapped epilogue, bf16 out.
struct QkvArgs {
  const float* A[3];
  const u16* B[3];
  const float* bias[3];
  float bscale[3];
  u16* C[3];
};

__global__ __launch_bounds__(256) void gemm_qkv(QkvArgs a) {
  const int z = blockIdx.z;
  const float* __restrict__ A = a.A[z];
  const u16* __restrict__ B = a.B[z];
  const float* __restrict__ bias = a.bias[z];
  const float bscale = a.bscale[z];
  u16* __restrict__ C = a.C[z];

  __shared__ u16 As[2][4096];
  __shared__ u16 Bs[2][4096];
  const int tid = threadIdx.x;
  const int lane = tid & 63;
  const int wave = tid >> 6;
  const int g = lane >> 4, c = lane & 15;
  const int g4 = g * 4;
  const int row0 = blockIdx.x * 128;
  const int col0 = blockIdx.y * 128;
  const int wr = (wave >> 1) * 64, wc = (wave & 1) * 64;

  const int ra = tid >> 2;              // A row within half-tile
  const int cca = (tid & 3) * 8;        // A k-offset

  f32x4 acc[4][4] = {};
  f32x4 ar[2][2];

#pragma unroll
  for (int i = 0; i < 2; ++i) {
    ar[i][0] = *(const f32x4*)(A + (size_t)(row0 + i * 64 + ra) * 1024 + cca);
    ar[i][1] = *(const f32x4*)(A + (size_t)(row0 + i * 64 + ra) * 1024 + cca + 4);
  }

  for (int s = 0; s < 32; ++s) {
    const int p = s & 1;
    const int k0 = s * 32;
    // convert + write A tile
#pragma unroll
    for (int i = 0; i < 2; ++i) {
      unsigned w0 = cvtpk_bf16(ar[i][0][0], ar[i][0][1]);
      unsigned w1 = cvtpk_bf16(ar[i][0][2], ar[i][0][3]);
      unsigned w2 = cvtpk_bf16(ar[i][1][0], ar[i][1][1]);
      unsigned w3 = cvtpk_bf16(ar[i][1][2], ar[i][1][3]);
      union { u32x4 u; s16x8 v; } w;
      w.u = (u32x4){w0, w1, w2, w3};
      *(s16x8*)(As[p] + (i * 256 + tid) * 8) = w.v;
    }
    // prefetch next A (fp32)
    if (s < 31) {
#pragma unroll
      for (int i = 0; i < 2; ++i) {
        ar[i][0] = *(const f32x4*)(A + (size_t)(row0 + i * 64 + ra) * 1024 + k0 + 32 + cca);
        ar[i][1] = *(const f32x4*)(A + (size_t)(row0 + i * 64 + ra) * 1024 + k0 + 32 + cca + 4);
      }
    }
    // stage B via global_load_lds
#pragma unroll
    for (int i = 0; i < 2; ++i) {
      int e = (i * 256 + tid) * 8;
      LDS_LOAD16(B + (size_t)(col0 + (e >> 5)) * 1024 + k0 + (e & 31), Bs[p] + e);
    }
    __syncthreads();   // drains gll + ds writes across block

    s16x8 af[4], bf[4];
#pragma unroll
    for (int m = 0; m < 4; ++m) af[m] = *(const s16x8*)(As[p] + (wr + m * 16 + c) * 32 + g * 8);
#pragma unroll
    for (int n = 0; n < 4; ++n) bf[n] = *(const s16x8*)(Bs[p] + (wc + n * 16 + c) * 32 + g * 8);
#pragma unroll
    for (int m = 0; m < 4; ++m)
#pragma unroll
      for (int n = 0; n < 4; ++n)
        acc[m][n] = MFMA16(bf[n], af[m], acc[m][n], 0, 0, 0);   // swapped
  }

  f32x4 bv[4];
#pragma unroll
  for (int n = 0; n < 4; ++n) {
    bv[n] = *(const f32x4*)(bias + col0 + wc + n * 16 + g4);
#pragma unroll
    for (int r = 0; r < 4; ++r) bv[n][r] *= bscale;
  }
#pragma unroll
  for (int m = 0; m < 4; ++m)
#pragma unroll
    for (int n = 0; n < 4; ++n) {
      s16x4 o;
#pragma unroll
      for (int r = 0; r < 4; ++r) o[r] = (short)f2bf(acc[m][n][r] + bv[n][r]);
      *(s16x4*)(C + (size_t)(row0 + wr + m * 16 + c) * 1024 + col0 + wc + n * 16 + g4) = o;
    }
}

// ---------------------------------------------------------------- out GEMM (proven R5)
__global__ __launch_bounds__(256) void gemm_out(const u16* __restrict__ A,
                                                const u16* __restrict__ B,
                                                const float* __restrict__ bias,
                                                const float* __restrict__ resid,
                                                float* __restrict__ C) {
  __shared__ u16 As[64 * 32];
  __shared__ u16 Bs[128 * 32];
  const int tid = threadIdx.x;
  const int lane = tid & 63;
  const int wave = tid >> 6;
  const int g = lane >> 4, c = lane & 15;
  const int g4 = g * 4;
  const int row0 = blockIdx.x * 64;
  const int col0 = blockIdx.y * 128;
  const int wr = (wave >> 1) * 32, wc = (wave & 1) * 64;

  f32x4 acc[2][4] = {};

  for (int k0 = 0; k0 < 1024; k0 += 32) {
    __syncthreads();
    LDS_LOAD16(A + (size_t)(row0 + (tid >> 2)) * 1024 + k0 + (tid & 3) * 8, As + tid * 8);
#pragma unroll
    for (int i = 0; i < 2; ++i) {
      int e = (i * 256 + tid) * 8;
      LDS_LOAD16(B + (size_t)(col0 + (e >> 5)) * 1024 + k0 + (e & 31), Bs + e);
    }
    __syncthreads();
    s16x8 af[2], bf[4];
#pragma unroll
    for (int m = 0; m < 2; ++m) af[m] = *(const s16x8*)(As + (wr + m * 16 + c) * 32 + g * 8);
#pragma unroll
    for (int n = 0; n < 4; ++n) bf[n] = *(const s16x8*)(Bs + (wc + n * 16 + c) * 32 + g * 8);
#pragma unroll
    for (int m = 0; m < 2; ++m)
#pragma unroll
      for (int n = 0; n < 4; ++n)
        acc[m][n] = MFMA16(bf[n], af[m], acc[m][n], 0, 0, 0);
  }

  f32x4 bv[4];
#pragma unroll
  for (int n = 0; n < 4; ++n) bv[n] = *(const f32x4*)(bias + col0 + wc + n * 16 + g4);
#pragma unroll
  for (int m = 0; m < 2; ++m)
#pragma unroll
    for (int n = 0; n < 4; ++n) {
      size_t off = (size_t)(row0 + wr + m * 16 + c) * 1024 + col0 + wc + n * 16 + g4;
      f32x4 rv = *(const f32x4*)(resid + off);
      f32x4 o;
#pragma unroll
      for (int r = 0; r < 4; ++r) o[r] = acc[m][n][r] + bv[n][r] + rv[r];
      *(f32x4*)(C + off) = o;
    }
}

// ---------------------------------------------------------------- attention
// Swapped-operand flash attention, KVBLK=64, 32 iters, ONE barrier/iter,
// K+V double-buffered LDS (reg-staged). ZERO-SHUFFLE PV: the MFMA contraction
// is invariant under k-slot relabeling applied to BOTH operands, so P stays in
// cvtpk register order (slot (g,j) -> k = 32ks+16(j>>2)+4g+(j&3)) and the V^T
// read supplies the same permutation via two ds_read_b64 per MFMA.
constexpr float NEGV = -10000000.0f;

__global__ __launch_bounds__(256) void attn_kernel(const u16* __restrict__ Qh,
                                                   const u16* __restrict__ Kh,
                                                   const u16* __restrict__ Vh,
                                                   const u64* __restrict__ mbits,
                                                   const float* __restrict__ head_mask,
                                                   u16* __restrict__ ctx) {
  __shared__ u16 Ks[2][4096];      // d-chunked: [chunk(d/8)][key(64)][d%8]
  __shared__ u16 Vt[2][64 * 72];   // [d][key ^ 8*(d>>3)], stride 72

  const int tid = threadIdx.x;
  const int lane = tid & 63;
  const int wave = tid >> 6;
  const int g = lane >> 4, c = lane & 15;
  const int g4 = g * 4;
  // XCD-chunked swizzle: 512 = 8 XCDs x 64; same-(b,h) blocks colocate per XCD
  const int wid = (blockIdx.x & 7) * 64 + (blockIdx.x >> 3);
  const int qt = wid & 15;
  const int bh = wid >> 4;
  const int b = bh >> 4;
  const int h = bh & 15;
  const size_t rowbase = (size_t)b * 2048;
  const int D = 1024;

  // Q B-fragments, 2 q-subtiles: lane(c,g) holds Q[q=c][ks*32+g*8+j]
  s16x8 qf[2][2];
#pragma unroll
  for (int s = 0; s < 2; ++s) {
    const int qrow = qt * 128 + s * 64 + wave * 16 + c;
#pragma unroll
    for (int ks = 0; ks < 2; ++ks)
      qf[s][ks] = *(const s16x8*)(Qh + (rowbase + qrow) * D + h * 64 + ks * 32 + g * 8);
  }

  f32x4 accO[2][4] = {};        // [set][d0]; col q=c, reg r <-> d=d0*16+g4+r
  float srun[2] = {0.f, 0.f};

  const u64* mrow0 = mbits + (rowbase + qt * 128 + 0 * 64 + wave * 16 + c) * 32;
  const u64* mrow1 = mbits + (rowbase + qt * 128 + 1 * 64 + wave * 16 + c) * 32;

  const int kkK = tid & 63;            // K staging: key; chunks wave, 4+wave
  const int aV = tid >> 3;             // V staging: key pair (2aV, 2aV+1)
  const int sV = tid & 7;
  const int dcV = sV * 8;
  const int colV = (2 * aV) ^ (8 * sV);

  const u16* Kbase = Kh + rowbase * D + h * 64;
  const u16* Vbase = Vh + rowbase * D + h * 64;

  s16x8 kreg[2], vreg[2];
#define LOADKV(kb_) { \
    kreg[0] = *(const s16x8*)(Kbase + (size_t)((kb_) + kkK) * D + wave * 8); \
    kreg[1] = *(const s16x8*)(Kbase + (size_t)((kb_) + kkK) * D + (4 + wave) * 8); \
    vreg[0] = *(const s16x8*)(Vbase + (size_t)((kb_) + 2 * aV) * D + dcV); \
    vreg[1] = *(const s16x8*)(Vbase + (size_t)((kb_) + 2 * aV + 1) * D + dcV); }
#define WRITEKV(p_) { \
    *(s16x8*)(Ks[p_] + tid * 8) = kreg[0]; \
    *(s16x8*)(Ks[p_] + 2048 + tid * 8) = kreg[1]; \
    _Pragma("unroll") \
    for (int j = 0; j < 8; ++j) { \
      unsigned pk = (unsigned)(u16)vreg[0][j] | ((unsigned)(u16)vreg[1][j] << 16); \
      *(unsigned*)(Vt[p_] + (dcV + j) * 72 + colV) = pk; } }

  LOADKV(0);
  WRITEKV(0);
  LOADKV(64);
  __syncthreads();

  for (int it = 0; it < 32; ++it) {
    const int p = it & 1;
    if (it < 31) WRITEKV(p ^ 1);       // regs from last iter; barrier made buf free
    if (it < 30) LOADKV((it + 2) * 64);

    // ---- S^T = K·Q^T: lane holds S[q=c][k = t*16 + g4 + r]
    f32x4 accS[2][4];
#pragma unroll
    for (int t = 0; t < 4; ++t) {
      s16x8 kf0 = *(const s16x8*)(Ks[p] + ((0 + g) * 64 + t * 16 + c) * 8);
      s16x8 kf1 = *(const s16x8*)(Ks[p] + ((4 + g) * 64 + t * 16 + c) * 8);
      f32x4 z0 = {0.f, 0.f, 0.f, 0.f};
      z0 = MFMA16(kf0, qf[0][0], z0, 0, 0, 0);
      accS[0][t] = MFMA16(kf1, qf[0][1], z0, 0, 0, 0);
      f32x4 z1 = {0.f, 0.f, 0.f, 0.f};
      z1 = MFMA16(kf0, qf[1][0], z1, 0, 0, 0);
      accS[1][t] = MFMA16(kf1, qf[1][1], z1, 0, 0, 0);
    }

    // ---- per-set: mask -> exp2 (Q pre-scaled by log2e) -> sum -> pack
    s16x8 pa[2][2];
#pragma unroll
    for (int s = 0; s < 2; ++s) {
      u64 mw = (s == 0 ? mrow0 : mrow1)[it];
      u64 sh = mw >> g4;
      unsigned mlo = (unsigned)sh, mhi = (unsigned)(sh >> 32);
      float sp = 0.f;
      unsigned pk0[4], pk1[4];
#pragma unroll
      for (int t = 0; t < 4; ++t) {
        unsigned msrc = (t < 2) ? mlo : mhi;
#pragma unroll
        for (int r = 0; r < 4; ++r) {
          float sv = accS[s][t][r];
          if ((msrc >> ((t & 1) * 16 + r)) & 1) sv = NEGV;
          float pv;
          asm("v_exp_f32 %0, %1" : "=v"(pv) : "v"(sv));   // 2^sv
          accS[s][t][r] = pv;
          sp += pv;
        }
        pk0[t] = cvtpk_bf16(accS[s][t][0], accS[s][t][1]);
        pk1[t] = cvtpk_bf16(accS[s][t][2], accS[s][t][3]);
      }
      srun[s] += sp;
      // zero-shuffle: slot (g,j) of pa[ks] holds k = 32ks + 16(j>>2) + 4g + (j&3)
#pragma unroll
      for (int ks = 0; ks < 2; ++ks) {
        union { u32x4 u; s16x8 v; } w;
        w.u = (u32x4){pk0[2 * ks], pk1[2 * ks], pk0[2 * ks + 1], pk1[2 * ks + 1]};
        pa[s][ks] = w.v;
      }
    }

    // ---- PV: vb supplies the SAME slot permutation via two b64 reads
#pragma unroll
    for (int d0 = 0; d0 < 4; ++d0) {
      const int dd = d0 * 16 + c;
      const int sw8 = (d0 * 2 + (c >> 3)) * 8;
#pragma unroll
      for (int ks = 0; ks < 2; ++ks) {
        const int base = ks * 32 + g4;
        u32x2 lo = *(const u32x2*)(Vt[p] + dd * 72 + (base ^ sw8));
        u32x2 hi = *(const u32x2*)(Vt[p] + dd * 72 + ((base + 16) ^ sw8));
        union { u32x4 u; s16x8 v; } w;
        w.u = (u32x4){lo[0], lo[1], hi[0], hi[1]};
        accO[0][d0] = MFMA16(w.v, pa[0][ks], accO[0][d0], 0, 0, 0);
        accO[1][d0] = MFMA16(w.v, pa[1][ks], accO[1][d0], 0, 0, 0);
      }
    }
    __syncthreads();
  }

  // ---- epilogue
  const float hm = head_mask[0];
#pragma unroll
  for (int s = 0; s < 2; ++s) {
    float tot = srun[s];
    tot += __shfl_xor(tot, 16, 64);
    tot += __shfl_xor(tot, 32, 64);
    float inv = hm / tot;
    const int qrow = qt * 128 + s * 64 + wave * 16 + c;
#pragma unroll
    for (int d0 = 0; d0 < 4; ++d0) {
      s16x4 o;
#pragma unroll
      for (int r = 0; r < 4; ++r) o[r] = (short)f2bf(accO[s][d0][r] * inv);
      *(s16x4*)(ctx + (rowbase + qrow) * D + h * 64 + d0 * 16 + g4) = o;
    }
  }
}

// ---------------------------------------------------------------- launch
extern "C" void kernel_launch(void* const* d_in, const int* in_sizes, int n_in,
                              void* d_out, int out_size, void* d_ws, size_t ws_size,
                              hipStream_t stream) {
  const float* q  = (const float*)d_in[0];
  const float* k  = (const float*)d_in[1];
  const float* v  = (const float*)d_in[2];
  const void*  am = d_in[3];
  const float* hm = (const float*)d_in[4];
  const float* Wq = (const float*)d_in[5];
  const float* bq = (const float*)d_in[6];
  const float* Wk = (const float*)d_in[7];
  const float* bk = (const float*)d_in[8];
  const float* Wv = (const float*)d_in[9];
  const float* bv = (const float*)d_in[10];
  const float* Wo = (const float*)d_in[11];
  const float* bo = (const float*)d_in[12];

  char* ws = (char*)d_ws;
  const size_t MB = 1024 * 1024;
  u16* Qh  = (u16*)(ws + 0 * MB);    // 8 MB
  u16* Kh  = (u16*)(ws + 8 * MB);    // 8 MB
  u16* Vh  = (u16*)(ws + 16 * MB);   // 8 MB
  u16* wqb = (u16*)(ws + 24 * MB);   // 2 MB each (wq pre-scaled 0.125*log2e)
  u16* wkb = (u16*)(ws + 26 * MB);
  u16* wvb = (u16*)(ws + 28 * MB);
  u16* wob = (u16*)(ws + 30 * MB);
  unsigned long long* mbits = (unsigned long long*)(ws + 32 * MB);  // 1 MB
  u16* ctx = (u16*)(ws + 33 * MB);   // 8 MB -> 41 MB total

  ConvArgs ca;
  ca.src[0] = Wq; ca.dst[0] = wqb; ca.scale[0] = 0.125f * L2E;
  ca.src[1] = Wk; ca.dst[1] = wkb; ca.scale[1] = 1.f;
  ca.src[2] = Wv; ca.dst[2] = wvb; ca.scale[2] = 1.f;
  ca.src[3] = Wo; ca.dst[3] = wob; ca.scale[3] = 1.f;
  convert_many<<<dim3(256, 4), 256, 0, stream>>>(ca);

  mask_to_bits<<<32768, 256, 0, stream>>>((const unsigned int*)am, mbits, 8388608);

  QkvArgs ga;
  ga.A[0] = q; ga.B[0] = wqb; ga.bias[0] = bq; ga.bscale[0] = 0.125f * L2E; ga.C[0] = Qh;
  ga.A[1] = k; ga.B[1] = wkb; ga.bias[1] = bk; ga.bscale[1] = 1.f;          ga.C[1] = Kh;
  ga.A[2] = v; ga.B[2] = wvb; ga.bias[2] = bv; ga.bscale[2] = 1.f;          ga.C[2] = Vh;
  gemm_qkv<<<dim3(32, 8, 3), 256, 0, stream>>>(ga);

  attn_kernel<<<512, 256, 0, stream>>>(Qh, Kh, Vh, mbits, hm, ctx);

  gemm_out<<<dim3(64, 8), 256, 0, stream>>>(ctx, wob, bo, q, (float*)d_out);
}